// Round 8
// baseline (417.069 us; speedup 1.0000x reference)
//
#include <hip/hip_runtime.h>
#include <hip/hip_bf16.h>
#include <hip/hip_cooperative_groups.h>

namespace cg = cooperative_groups;

typedef __hip_bfloat16 bf16;
typedef __attribute__((ext_vector_type(8))) short short8;
typedef __attribute__((ext_vector_type(4))) short sh4;
typedef __attribute__((ext_vector_type(4))) float f32x4;

static __device__ __forceinline__ float bf2f(bf16 h) { return __bfloat162float(h); }
static __device__ __forceinline__ short f2bfs(float f) {
    bf16 h = __float2bfloat16(f);
    return *reinterpret_cast<short*>(&h);
}

constexpr int Bn = 8;
constexpr int C  = 256;
constexpr int N  = 1024;     // H*W
constexpr int NH = 8;
constexpr int HD = 32;
constexpr float SCALE = 0.17677669529663687f;  // 1/sqrt(32)

// LDS: max member 9216 B -> >=4 blocks/CU even under a 64KB-per-CU
// occupancy assumption (VGPR cap 128 from launch_bounds is the binder).
union alignas(16) SharedU {
    short T[16 * 264];                      // transpose tile [pixel][c], 8448 B
    struct { float wq[1024]; float wk[1024]; } g;  // gate weights, 8192 B
    short P[4][16 * 72];                    // per-wave P [q(16)][key(64)], 9216 B
};

// ---------------------------------------------------------------------------
// Mega-kernel, phase in {-1 = all w/ grid.sync, 0..3 = single phase}.
// Phase 0 (T): x -> xb[B][N][C] bf16 (512 units), gates (32 units),
//              W -> Wb bf16 (16 units).
// Phase 1 (A): q/k/v MFMA GEMM, 1536 units of 64m x 64n.
// Phase 2 (B): flash attention + gated mix, 1024 units of 64 queries.
// Phase 3 (C): projection MFMA GEMM, 512 units of 64m x 64n.
// All unit loops stride by gridDim.x -> any grid size is correct.
// ---------------------------------------------------------------------------
__global__ __launch_bounds__(256, 4) void k_mega(
    const float* __restrict__ x, const float* __restrict__ gq, const float* __restrict__ gk,
    const float* __restrict__ Wsq, const float* __restrict__ bsq,
    const float* __restrict__ Wsk, const float* __restrict__ bsk,
    const float* __restrict__ Wq, const float* __restrict__ bq,
    const float* __restrict__ Wk, const float* __restrict__ bk,
    const float* __restrict__ Wv, const float* __restrict__ bv,
    const float* __restrict__ Wp, const float* __restrict__ bp,
    bf16* __restrict__ xb, bf16* __restrict__ Wb,
    float* __restrict__ sq, float* __restrict__ sk,
    bf16* __restrict__ qo, bf16* __restrict__ ko, bf16* __restrict__ vo,
    bf16* __restrict__ gt, float* __restrict__ out, int phase)
{
    __shared__ SharedU sh;
    cg::grid_group grid = cg::this_grid();

    const int tid  = threadIdx.x;
    const int wave = tid >> 6;
    const int lane = tid & 63;
    const int col  = lane & 15;
    const int quad = lane >> 4;

    // ===================== Phase T =====================
    if (phase == -1 || phase == 0) {
        for (int u = blockIdx.x; u < 560; u += gridDim.x) {
            if (u < 512) {
                // transpose 16 pixels x 256 c
                const int b  = u >> 6;
                const int n0 = (u & 63) * 16;
                const float* xp = x + (size_t)b * C * N;
                __syncthreads();
                {
                    const int cr = tid >> 2, nf = (tid & 3) * 4;
#pragma unroll
                    for (int p = 0; p < 4; ++p) {
                        int c = p * 64 + cr;
                        float4 v = *reinterpret_cast<const float4*>(xp + (size_t)c * N + n0 + nf);
                        sh.T[(nf + 0) * 264 + c] = f2bfs(v.x);
                        sh.T[(nf + 1) * 264 + c] = f2bfs(v.y);
                        sh.T[(nf + 2) * 264 + c] = f2bfs(v.z);
                        sh.T[(nf + 3) * 264 + c] = f2bfs(v.w);
                    }
                }
                __syncthreads();
                {
                    const int n = tid >> 4, c0 = (tid & 15) * 16;
                    short* op = reinterpret_cast<short*>(xb) + ((size_t)b * N + n0) * C;
                    short8 v0 = *reinterpret_cast<const short8*>(&sh.T[n * 264 + c0]);
                    short8 v1 = *reinterpret_cast<const short8*>(&sh.T[n * 264 + c0 + 8]);
                    *reinterpret_cast<short8*>(op + (size_t)n * C + c0)     = v0;
                    *reinterpret_cast<short8*>(op + (size_t)n * C + c0 + 8) = v1;
                }
            } else if (u < 544) {
                // gates: 256 pixels per unit, 1 thread/pixel (reads x directly)
                const int gu = u - 512;
                const int b  = gu >> 2;
                const int n  = (gu & 3) * 256 + tid;
                __syncthreads();
#pragma unroll
                for (int i = 0; i < 4; ++i) {
                    int j = tid + 256 * i;
                    sh.g.wq[j] = Wsq[j];
                    sh.g.wk[j] = Wsk[j];
                }
                __syncthreads();
                const float* xp = x + (size_t)b * C * N + n;
                float aq[4], ak[4];
#pragma unroll
                for (int s = 0; s < 4; ++s) { aq[s] = 0.f; ak[s] = 0.f; }
                for (int c4 = 0; c4 < C; c4 += 4) {
                    float xv[4];
#pragma unroll
                    for (int v = 0; v < 4; ++v) xv[v] = xp[(size_t)(c4 + v) * N];
#pragma unroll
                    for (int s = 0; s < 4; ++s) {
                        float4 w4 = *reinterpret_cast<const float4*>(&sh.g.wq[s * C + c4]);
                        aq[s] += w4.x * xv[0] + w4.y * xv[1] + w4.z * xv[2] + w4.w * xv[3];
                        float4 k4 = *reinterpret_cast<const float4*>(&sh.g.wk[s * C + c4]);
                        ak[s] += k4.x * xv[0] + k4.y * xv[1] + k4.z * xv[2] + k4.w * xv[3];
                    }
                }
#pragma unroll
                for (int s = 0; s < 4; ++s) {
                    aq[s] += bsq[s] + gq[(size_t)b * 4 * N + (size_t)s * N + n];
                    ak[s] += bsk[s] + gk[(size_t)b * 4 * N + (size_t)s * N + n];
                }
                float mq = fmaxf(fmaxf(aq[0], aq[1]), fmaxf(aq[2], aq[3]));
                float mk = fmaxf(fmaxf(ak[0], ak[1]), fmaxf(ak[2], ak[3]));
                float eq = 0.f, ek = 0.f;
#pragma unroll
                for (int s = 0; s < 4; ++s) { eq += __expf(aq[s] - mq); ek += __expf(ak[s] - mk); }
                sq[b * N + n] = __expf(aq[0] - mq) / eq;
                sk[b * N + n] = __expf(ak[0] - mk) / ek;
            } else {
                // W convert, 16 units
                const int wi = u - 544;
                const int mat = wi >> 2, seg = wi & 3;
                const float* src = (mat == 0) ? Wq : (mat == 1) ? Wk : (mat == 2) ? Wv : Wp;
                short* dst = reinterpret_cast<short*>(Wb) + (size_t)mat * 256 * 256;
#pragma unroll
                for (int i = 0; i < 16; ++i) {
                    int f4 = seg * 4096 + i * 256 + tid;
                    float4 v = reinterpret_cast<const float4*>(src)[f4];
                    sh4 o;
                    o[0] = f2bfs(v.x); o[1] = f2bfs(v.y); o[2] = f2bfs(v.z); o[3] = f2bfs(v.w);
                    *reinterpret_cast<sh4*>(dst + (size_t)f4 * 4) = o;
                }
            }
        }
    }

    if (phase == -1) grid.sync();

    // ===================== Phase A: q/k/v GEMM =====================
    if (phase == -1 || phase == 1) {
        for (int u = blockIdx.x; u < 1536; u += gridDim.x) {
            const int mt = u % 12;
            const int r  = u / 12;
            const int mat  = mt >> 2;
            const int mrow = (mt & 3) * 64;
            const int n0   = (r & 15) * 64;
            const int b    = r >> 4;
            const short* Wm = reinterpret_cast<const short*>(Wb) + (size_t)mat * 256 * 256;
            const short* xp = reinterpret_cast<const short*>(xb) + (size_t)b * N * C;
            const int m16 = mrow + wave * 16;

            f32x4 acc[4] = {};
#pragma unroll
            for (int k0 = 0; k0 < 256; k0 += 32) {
                short8 af = *reinterpret_cast<const short8*>(Wm + (size_t)(m16 + col) * 256 + k0 + quad * 8);
#pragma unroll
                for (int cf = 0; cf < 4; ++cf) {
                    short8 bfr = *reinterpret_cast<const short8*>(xp + (size_t)(n0 + cf * 16 + col) * C + k0 + quad * 8);
                    acc[cf] = __builtin_amdgcn_mfma_f32_16x16x32_bf16(af, bfr, acc[cf], 0, 0, 0);
                }
            }
            const float* bb = (mat == 0) ? bq : (mat == 1) ? bk : bv;
            float bias[4];
#pragma unroll
            for (int r2 = 0; r2 < 4; ++r2) bias[r2] = bb[m16 + quad * 4 + r2];
            if (mat < 2) {
                const float* gsrc = (mat == 0) ? sq : sk;
                const float gm = (mat == 0) ? SCALE : 1.f;
                short* op = reinterpret_cast<short*>((mat == 0) ? qo : ko) + (size_t)b * N * C;
#pragma unroll
                for (int cf = 0; cf < 4; ++cf) {
                    int n = n0 + cf * 16 + col;
                    float g = gsrc[b * N + n] * gm;
                    sh4 pack;
#pragma unroll
                    for (int r2 = 0; r2 < 4; ++r2) pack[r2] = f2bfs((acc[cf][r2] + bias[r2]) * g);
                    *reinterpret_cast<sh4*>(op + (size_t)n * C + m16 + quad * 4) = pack;
                }
            } else {
                bf16* op = vo + (size_t)b * C * N;
#pragma unroll
                for (int cf = 0; cf < 4; ++cf) {
                    int n = n0 + cf * 16 + col;
#pragma unroll
                    for (int r2 = 0; r2 < 4; ++r2) {
                        int c = m16 + quad * 4 + r2;
                        op[(size_t)c * N + n] = __float2bfloat16(acc[cf][r2] + bias[r2]);
                    }
                }
            }
        }
    }

    if (phase == -1) grid.sync();

    // ===================== Phase B: attention =====================
    if (phase == -1 || phase == 2) {
        for (int u = blockIdx.x; u < 1024; u += gridDim.x) {
            const int b = u >> 7;
            const int h = (u >> 4) & 7;
            const int qbase = (u & 15) * 64 + wave * 16;

            const short* kp = reinterpret_cast<const short*>(ko) + (size_t)b * N * C + h * HD + quad * 8;
            const short* vp = reinterpret_cast<const short*>(vo) + (size_t)b * C * N + (size_t)h * HD * N;

            short8 qf;
            {
                const short* qp = reinterpret_cast<const short*>(qo) + (size_t)b * N * C + h * HD + quad * 8;
                qf = *reinterpret_cast<const short8*>(qp + (size_t)(qbase + col) * C);
            }

            float l = 0.f;
            f32x4 o_acc[2] = {};
            short* P = sh.P[wave];

            short8 kf[4];
#pragma unroll
            for (int c = 0; c < 4; ++c)
                kf[c] = *reinterpret_cast<const short8*>(kp + (size_t)(c * 16 + col) * C);

            for (int kbase = 0; kbase < N; kbase += 64) {
                short8 vf[2][2];
#pragma unroll
                for (int kg = 0; kg < 2; ++kg)
#pragma unroll
                    for (int dh = 0; dh < 2; ++dh)
                        vf[kg][dh] = *reinterpret_cast<const short8*>(vp + (size_t)(dh * 16 + col) * N + kbase + kg * 32 + quad * 8);

                float s[16];
#pragma unroll
                for (int c = 0; c < 4; ++c) {
                    f32x4 acc = {};
                    acc = __builtin_amdgcn_mfma_f32_16x16x32_bf16(kf[c], qf, acc, 0, 0, 0);
#pragma unroll
                    for (int r = 0; r < 4; ++r) s[c * 4 + r] = acc[r];
                }
                float p[16], lloc = 0.f;
#pragma unroll
                for (int i = 0; i < 16; ++i) { p[i] = __expf(s[i]); lloc += p[i]; }
                lloc += __shfl_xor(lloc, 16, 64);
                lloc += __shfl_xor(lloc, 32, 64);
                l += lloc;
#pragma unroll
                for (int c = 0; c < 4; ++c) {
                    sh4 pk;
#pragma unroll
                    for (int r = 0; r < 4; ++r) pk[r] = f2bfs(p[c * 4 + r]);
                    *reinterpret_cast<sh4*>(&P[col * 72 + c * 16 + quad * 4]) = pk;
                }

                const int knext = (kbase + 64) & (N - 1);
#pragma unroll
                for (int c = 0; c < 4; ++c)
                    kf[c] = *reinterpret_cast<const short8*>(kp + (size_t)(knext + c * 16 + col) * C);

#pragma unroll
                for (int kg = 0; kg < 2; ++kg) {
                    short8 pf = *reinterpret_cast<const short8*>(&P[col * 72 + kg * 32 + quad * 8]);
#pragma unroll
                    for (int dh = 0; dh < 2; ++dh)
                        o_acc[dh] = __builtin_amdgcn_mfma_f32_16x16x32_bf16(vf[kg][dh], pf, o_acc[dh], 0, 0, 0);
                }
            }

            const int q = qbase + col;
            const float invl = 1.f / l;
            const float sqv  = sq[b * N + q];
            const float hv   = 1.f - sqv;
            short* gp = reinterpret_cast<short*>(gt) + ((size_t)b * N + q) * C + h * HD + quad * 4;
#pragma unroll
            for (int dh = 0; dh < 2; ++dh) {
                sh4 pack;
#pragma unroll
                for (int r = 0; r < 4; ++r) {
                    int d = dh * 16 + quad * 4 + r;
                    float vb = bf2f(*reinterpret_cast<const bf16*>(vp + (size_t)d * N + q));
                    pack[r] = f2bfs(sqv * (o_acc[dh][r] * invl) + hv * vb);
                }
                *reinterpret_cast<sh4*>(gp + dh * 16) = pack;
            }
        }
    }

    if (phase == -1) grid.sync();

    // ===================== Phase C: projection =====================
    if (phase == -1 || phase == 3) {
        for (int u = blockIdx.x; u < 512; u += gridDim.x) {
            const int mrow = (u & 3) * 64;
            const int n0   = ((u >> 2) & 15) * 64;
            const int b    = u >> 6;
            const short* Wm = reinterpret_cast<const short*>(Wb) + (size_t)3 * 256 * 256;
            const short* gp = reinterpret_cast<const short*>(gt) + (size_t)b * N * C;
            const int m16 = mrow + wave * 16;

            f32x4 acc[4] = {};
#pragma unroll
            for (int k0 = 0; k0 < 256; k0 += 32) {
                short8 af = *reinterpret_cast<const short8*>(Wm + (size_t)(m16 + col) * 256 + k0 + quad * 8);
#pragma unroll
                for (int cf = 0; cf < 4; ++cf) {
                    short8 bfr = *reinterpret_cast<const short8*>(gp + (size_t)(n0 + cf * 16 + col) * C + k0 + quad * 8);
                    acc[cf] = __builtin_amdgcn_mfma_f32_16x16x32_bf16(af, bfr, acc[cf], 0, 0, 0);
                }
            }
            float bias[4];
#pragma unroll
            for (int r = 0; r < 4; ++r) bias[r] = bp[m16 + quad * 4 + r];
            float* op = out + (size_t)b * C * N;
#pragma unroll
            for (int cf = 0; cf < 4; ++cf) {
                int n = n0 + cf * 16 + col;
#pragma unroll
                for (int r = 0; r < 4; ++r) {
                    int c = m16 + quad * 4 + r;
                    op[(size_t)c * N + n] = acc[cf][r] + bias[r];
                }
            }
        }
    }
}

// ---------------------------------------------------------------------------
// Workspace: sq|sk f32[8][1024]; xb bf16[8][1024][256]; Wb bf16[4][256][256];
// qo,ko pixel-major bf16; vo d-major bf16; gt pixel-major bf16.
// ---------------------------------------------------------------------------
extern "C" void kernel_launch(void* const* d_in, const int* in_sizes, int n_in,
                              void* d_out, int out_size, void* d_ws, size_t ws_size,
                              hipStream_t stream)
{
    const float* x   = (const float*)d_in[0];
    const float* gq  = (const float*)d_in[1];
    const float* gk  = (const float*)d_in[2];
    const float* Wsq = (const float*)d_in[3];
    const float* bsq = (const float*)d_in[4];
    const float* Wsk = (const float*)d_in[5];
    const float* bsk = (const float*)d_in[6];
    const float* Wq  = (const float*)d_in[7];
    const float* bq  = (const float*)d_in[8];
    const float* Wk  = (const float*)d_in[9];
    const float* bk  = (const float*)d_in[10];
    const float* Wv  = (const float*)d_in[11];
    const float* bv  = (const float*)d_in[12];
    const float* Wp  = (const float*)d_in[13];
    const float* bp  = (const float*)d_in[14];

    char* ws = (char*)d_ws;
    float* sq = (float*)ws;
    float* sk = (float*)(ws + 32768);
    bf16* xb  = (bf16*)(ws + 65536);
    bf16* Wb  = xb + (size_t)Bn * N * C;
    bf16* qo  = Wb + 4 * 256 * 256;
    bf16* ko  = qo + (size_t)Bn * N * C;
    bf16* vo  = ko + (size_t)Bn * N * C;
    bf16* gt  = vo + (size_t)Bn * C * N;
    float* out = (float*)d_out;

    // Deterministic host-side occupancy probe (no device work; graph-safe).
    int maxB = 0;
    hipError_t oe = hipOccupancyMaxActiveBlocksPerMultiprocessor(
        &maxB, reinterpret_cast<const void*>(k_mega), 256, 0);
    if (oe != hipSuccess) maxB = 0;

    int gridX = 1024;
    if (maxB > 0 && maxB * 256 < gridX) gridX = maxB * 256;

    hipError_t le = hipErrorUnknown;
    if (maxB > 0) {
        int phase_all = -1;
        void* args[] = {
            (void*)&x, (void*)&gq, (void*)&gk,
            (void*)&Wsq, (void*)&bsq, (void*)&Wsk, (void*)&bsk,
            (void*)&Wq, (void*)&bq, (void*)&Wk, (void*)&bk,
            (void*)&Wv, (void*)&bv, (void*)&Wp, (void*)&bp,
            (void*)&xb, (void*)&Wb, (void*)&sq, (void*)&sk,
            (void*)&qo, (void*)&ko, (void*)&vo, (void*)&gt, (void*)&out,
            (void*)&phase_all
        };
        le = hipLaunchCooperativeKernel((void*)k_mega, dim3(gridX), dim3(256),
                                        args, 0, stream);
    }
    if (le != hipSuccess) {
        // Fallback: same kernel, one launch per phase (kernel boundary = sync).
        for (int ph = 0; ph < 4; ++ph) {
            k_mega<<<dim3(1024), dim3(256), 0, stream>>>(
                x, gq, gk, Wsq, bsq, Wsk, bsk, Wq, bq, Wk, bk, Wv, bv, Wp, bp,
                xb, Wb, sq, sk, qo, ko, vo, gt, out, ph);
        }
    }
}

// Round 9
// 167.689 us; speedup vs baseline: 2.4872x; 2.4872x over previous
//
#include <hip/hip_runtime.h>
#include <hip/hip_bf16.h>

typedef __hip_bfloat16 bf16;
typedef __attribute__((ext_vector_type(8))) short short8;
typedef __attribute__((ext_vector_type(4))) short sh4;
typedef __attribute__((ext_vector_type(4))) float f32x4;

static __device__ __forceinline__ float bf2f(bf16 h) { return __bfloat162float(h); }
static __device__ __forceinline__ short f2bfs(float f) {
    bf16 h = __float2bfloat16(f);
    return *reinterpret_cast<short*>(&h);
}
static __device__ __forceinline__ short8 cvt8(float4 a, float4 b) {
    short8 o;
    o[0] = f2bfs(a.x); o[1] = f2bfs(a.y); o[2] = f2bfs(a.z); o[3] = f2bfs(a.w);
    o[4] = f2bfs(b.x); o[5] = f2bfs(b.y); o[6] = f2bfs(b.z); o[7] = f2bfs(b.w);
    return o;
}

constexpr int Bn = 8;
constexpr int C  = 256;
constexpr int N  = 1024;     // H*W
constexpr int NH = 8;
constexpr int HD = 32;
constexpr int TS = 264;      // LDS tile stride (shorts)
constexpr float SCALE = 0.17677669529663687f;  // 1/sqrt(32)

// ---------------------------------------------------------------------------
// K1: fused transpose + gates + q/k/v GEMM.
// blocks 0..255: (b, 32-pixel tile). Stage x^T tile in LDS; wave0 computes
//   gumbel gates for the 32 pixels via one extra MFMA pair (A rows =
//   [Wsq(4); Wsk(4); dup]) + lane-local softmax; all waves then run the
//   M=768 (q|k|v) GEMM with A-frags converted from f32 W on the fly and
//   B-frags read from the LDS tile. Epilogue folds bias + gates (+SCALE).
//   q,k stored pixel-major [B][N][C]; v stored d-major [B][C][N].
// blocks 256..259: convert Wp f32 -> Wpb bf16 (for K2).
// ---------------------------------------------------------------------------
__global__ void k_fused(
    const float* __restrict__ x, const float* __restrict__ gq, const float* __restrict__ gk,
    const float* __restrict__ Wsq, const float* __restrict__ bsq,
    const float* __restrict__ Wsk, const float* __restrict__ bsk,
    const float* __restrict__ Wq, const float* __restrict__ bq,
    const float* __restrict__ Wk, const float* __restrict__ bk,
    const float* __restrict__ Wv, const float* __restrict__ bv,
    const float* __restrict__ Wp,
    bf16* __restrict__ qo, bf16* __restrict__ ko, bf16* __restrict__ vo,
    bf16* __restrict__ Wpb, float* __restrict__ sqg)
{
    const int bx  = blockIdx.x;
    const int tid = threadIdx.x;

    if (bx >= 256) {   // Wp convert
        const int seg = bx - 256;
        short* dst = reinterpret_cast<short*>(Wpb);
#pragma unroll
        for (int i = 0; i < 16; ++i) {
            int f4 = seg * 4096 + i * 256 + tid;
            float4 v = reinterpret_cast<const float4*>(Wp)[f4];
            sh4 o;
            o[0] = f2bfs(v.x); o[1] = f2bfs(v.y); o[2] = f2bfs(v.z); o[3] = f2bfs(v.w);
            *reinterpret_cast<sh4*>(dst + (size_t)f4 * 4) = o;
        }
        return;
    }

    __shared__ short T[32 * TS];     // [pixel][c]
    __shared__ float sq_lds[32];
    __shared__ float sk_lds[32];

    const int wave = tid >> 6;
    const int lane = tid & 63;
    const int col  = lane & 15;
    const int quad = lane >> 4;

    const int b  = bx >> 5;
    const int n0 = (bx & 31) * 32;

    // ---- stage x^T tile: 256 c-rows x 32 pixels ----
    {
        const float* xp = x + (size_t)b * C * N + n0;
        const int row = tid >> 3;        // c within pass
        const int f   = tid & 7;         // float4 within 32 pixels
#pragma unroll
        for (int p = 0; p < 8; ++p) {
            int c = p * 32 + row;
            float4 v = *reinterpret_cast<const float4*>(xp + (size_t)c * N + f * 4);
            T[(f * 4 + 0) * TS + c] = f2bfs(v.x);
            T[(f * 4 + 1) * TS + c] = f2bfs(v.y);
            T[(f * 4 + 2) * TS + c] = f2bfs(v.z);
            T[(f * 4 + 3) * TS + c] = f2bfs(v.w);
        }
    }
    __syncthreads();

    // ---- gates (wave 0 only): logits via MFMA, lane-local softmax ----
    if (wave == 0) {
        const float* wsrc = (col < 4) ? (Wsq + col * C) : (Wsk + (col & 3) * C);
        f32x4 ga[2] = {};
#pragma unroll
        for (int k0 = 0; k0 < 256; k0 += 32) {
            float4 w0 = *reinterpret_cast<const float4*>(wsrc + k0 + quad * 8);
            float4 w1 = *reinterpret_cast<const float4*>(wsrc + k0 + quad * 8 + 4);
            short8 af = cvt8(w0, w1);
            short8 b0 = *reinterpret_cast<const short8*>(&T[col * TS + k0 + quad * 8]);
            short8 b1 = *reinterpret_cast<const short8*>(&T[(16 + col) * TS + k0 + quad * 8]);
            ga[0] = __builtin_amdgcn_mfma_f32_16x16x32_bf16(af, b0, ga[0], 0, 0, 0);
            ga[1] = __builtin_amdgcn_mfma_f32_16x16x32_bf16(af, b1, ga[1], 0, 0, 0);
        }
        if (quad < 2) {
            const float* bsrc = (quad == 0) ? bsq : bsk;
            const float* gsrc = (quad == 0) ? gq : gk;
#pragma unroll
            for (int cf = 0; cf < 2; ++cf) {
                int n = n0 + cf * 16 + col;
                float a[4];
#pragma unroll
                for (int r = 0; r < 4; ++r)
                    a[r] = ga[cf][r] + bsrc[r] + gsrc[(size_t)b * 4 * N + (size_t)r * N + n];
                float mx = fmaxf(fmaxf(a[0], a[1]), fmaxf(a[2], a[3]));
                float e = 0.f;
#pragma unroll
                for (int r = 0; r < 4; ++r) e += __expf(a[r] - mx);
                float p0 = __expf(a[0] - mx) / e;
                if (quad == 0) { sq_lds[cf * 16 + col] = p0; sqg[b * N + n] = p0; }
                else            sk_lds[cf * 16 + col] = p0;
            }
        }
    }
    __syncthreads();

    // ---- main GEMM: M=768 over 4 waves x 2 halves of 6 frags ----
#pragma unroll
    for (int half = 0; half < 2; ++half) {
        const int mbase = wave * 192 + half * 96;
        f32x4 acc[6][2] = {};
#pragma unroll
        for (int k0 = 0; k0 < 256; k0 += 32) {
            short8 b0 = *reinterpret_cast<const short8*>(&T[col * TS + k0 + quad * 8]);
            short8 b1 = *reinterpret_cast<const short8*>(&T[(16 + col) * TS + k0 + quad * 8]);
#pragma unroll
            for (int i = 0; i < 6; ++i) {
                int m = mbase + i * 16;
                const float* wsrc = (m < 256) ? Wq : (m < 512) ? Wk : Wv;
                const float* wr = wsrc + (size_t)((m & 255) + col) * 256 + k0 + quad * 8;
                float4 w0 = *reinterpret_cast<const float4*>(wr);
                float4 w1 = *reinterpret_cast<const float4*>(wr + 4);
                short8 af = cvt8(w0, w1);
                acc[i][0] = __builtin_amdgcn_mfma_f32_16x16x32_bf16(af, b0, acc[i][0], 0, 0, 0);
                acc[i][1] = __builtin_amdgcn_mfma_f32_16x16x32_bf16(af, b1, acc[i][1], 0, 0, 0);
            }
        }
        // epilogue for these 6 frags
#pragma unroll
        for (int i = 0; i < 6; ++i) {
            int m = mbase + i * 16;
            int mat = m >> 8;
            int cr  = (m & 255) + quad * 4;
            const float* bb = (mat == 0) ? bq : (mat == 1) ? bk : bv;
            float bias[4];
#pragma unroll
            for (int r = 0; r < 4; ++r) bias[r] = bb[cr + r];
            if (mat < 2) {
                short* op = reinterpret_cast<short*>((mat == 0) ? qo : ko) + (size_t)b * N * C;
#pragma unroll
                for (int cf = 0; cf < 2; ++cf) {
                    int n = n0 + cf * 16 + col;
                    float g = (mat == 0) ? sq_lds[cf * 16 + col] * SCALE
                                         : sk_lds[cf * 16 + col];
                    sh4 pack;
#pragma unroll
                    for (int r = 0; r < 4; ++r) pack[r] = f2bfs((acc[i][cf][r] + bias[r]) * g);
                    *reinterpret_cast<sh4*>(op + (size_t)n * C + cr) = pack;
                }
            } else {
                bf16* op = vo + (size_t)b * C * N;
#pragma unroll
                for (int cf = 0; cf < 2; ++cf) {
                    int n = n0 + cf * 16 + col;
#pragma unroll
                    for (int r = 0; r < 4; ++r)
                        op[(size_t)(cr + r) * N + n] = __float2bfloat16(acc[i][cf][r] + bias[r]);
                }
            }
        }
    }
}

// ---------------------------------------------------------------------------
// K2: fused attention (all 8 heads per block) + gated mix + projection.
// Block = (b, 32-query tile); wave w handles heads {2w, 2w+1} over all 32
// queries. P round-trips per-wave LDS (stride 72, verified conflict-light).
// After attention, gated rows staged to LDS G[32][264] (union with P),
// then the projection GEMM runs in-block (A = Wpb bf16 direct, B = G).
// ---------------------------------------------------------------------------
union SharedK2 {
    short P[4][32 * 72];    // per-wave [query(32)][key(64)]
    short G[32 * TS];       // gated rows [pixel][c]
};

__global__ void k_attnproj(
    const bf16* __restrict__ qo, const bf16* __restrict__ ko,
    const bf16* __restrict__ vo, const float* __restrict__ sqg,
    const bf16* __restrict__ Wpb, const float* __restrict__ bp,
    float* __restrict__ out)
{
    __shared__ SharedK2 sh;
    const int tid  = threadIdx.x;
    const int wave = tid >> 6;
    const int lane = tid & 63;
    const int col  = lane & 15;
    const int quad = lane >> 4;

    const int b  = blockIdx.x >> 5;
    const int n0 = (blockIdx.x & 31) * 32;

    const short* qbase = reinterpret_cast<const short*>(qo) + (size_t)b * N * C;
    const short* kbase_p = reinterpret_cast<const short*>(ko) + (size_t)b * N * C;
    const short* vbase = reinterpret_cast<const short*>(vo) + (size_t)b * C * N;

    float l[2][2] = {};
    f32x4 oac[2][2][2] = {};   // [hh][g][dh]
    short* P = sh.P[wave];

#pragma unroll
    for (int hh = 0; hh < 2; ++hh) {
        const int h = wave * 2 + hh;
        const short* kp = kbase_p + h * HD + quad * 8;
        const short* vp = vbase + (size_t)h * HD * N;

        short8 qf[2];
#pragma unroll
        for (int g = 0; g < 2; ++g)
            qf[g] = *reinterpret_cast<const short8*>(qbase + (size_t)(n0 + g * 16 + col) * C + h * HD + quad * 8);

        short8 kf[4];
#pragma unroll
        for (int c = 0; c < 4; ++c)
            kf[c] = *reinterpret_cast<const short8*>(kp + (size_t)(c * 16 + col) * C);

        for (int kb = 0; kb < N; kb += 64) {
            short8 vf[2][2];
#pragma unroll
            for (int kg = 0; kg < 2; ++kg)
#pragma unroll
                for (int dh = 0; dh < 2; ++dh)
                    vf[kg][dh] = *reinterpret_cast<const short8*>(vp + (size_t)(dh * 16 + col) * N + kb + kg * 32 + quad * 8);

#pragma unroll
            for (int g = 0; g < 2; ++g) {
                float s[16];
#pragma unroll
                for (int c = 0; c < 4; ++c) {
                    f32x4 acc = {};
                    acc = __builtin_amdgcn_mfma_f32_16x16x32_bf16(kf[c], qf[g], acc, 0, 0, 0);
#pragma unroll
                    for (int r = 0; r < 4; ++r) s[c * 4 + r] = acc[r];
                }
                float p[16], lloc = 0.f;
#pragma unroll
                for (int i = 0; i < 16; ++i) { p[i] = __expf(s[i]); lloc += p[i]; }
                lloc += __shfl_xor(lloc, 16, 64);
                lloc += __shfl_xor(lloc, 32, 64);
                l[hh][g] += lloc;
#pragma unroll
                for (int c = 0; c < 4; ++c) {
                    sh4 pk;
#pragma unroll
                    for (int r = 0; r < 4; ++r) pk[r] = f2bfs(p[c * 4 + r]);
                    *reinterpret_cast<sh4*>(&P[(g * 16 + col) * 72 + c * 16 + quad * 4]) = pk;
                }
            }

            const int kn = (kb + 64) & (N - 1);
#pragma unroll
            for (int c = 0; c < 4; ++c)
                kf[c] = *reinterpret_cast<const short8*>(kp + (size_t)(kn + c * 16 + col) * C);

#pragma unroll
            for (int kg = 0; kg < 2; ++kg) {
#pragma unroll
                for (int g = 0; g < 2; ++g) {
                    short8 pf = *reinterpret_cast<const short8*>(&P[(g * 16 + col) * 72 + kg * 32 + quad * 8]);
#pragma unroll
                    for (int dh = 0; dh < 2; ++dh)
                        oac[hh][g][dh] = __builtin_amdgcn_mfma_f32_16x16x32_bf16(vf[kg][dh], pf, oac[hh][g][dh], 0, 0, 0);
                }
            }
        }
    }

    __syncthreads();   // all waves done with P; safe to overwrite union with G

    // gated mix -> G
#pragma unroll
    for (int hh = 0; hh < 2; ++hh) {
        const int h = wave * 2 + hh;
        const short* vp = reinterpret_cast<const short*>(vbase) + (size_t)h * HD * N;
#pragma unroll
        for (int g = 0; g < 2; ++g) {
            const int q = n0 + g * 16 + col;
            const float invl = 1.f / l[hh][g];
            const float sqv  = sqg[b * N + q];
            const float hv   = 1.f - sqv;
#pragma unroll
            for (int dh = 0; dh < 2; ++dh) {
                sh4 pack;
#pragma unroll
                for (int r = 0; r < 4; ++r) {
                    int d = dh * 16 + quad * 4 + r;
                    float vb = bf2f(*reinterpret_cast<const bf16*>(vp + (size_t)d * N + q));
                    pack[r] = f2bfs(sqv * (oac[hh][g][dh][r] * invl) + hv * vb);
                }
                *reinterpret_cast<sh4*>(&sh.G[(g * 16 + col) * TS + h * HD + dh * 16 + quad * 4]) = pack;
            }
        }
    }

    __syncthreads();

    // projection GEMM: out = Wp @ G + bp
    const short* Wm = reinterpret_cast<const short*>(Wpb);
    f32x4 pacc[4][2] = {};
#pragma unroll
    for (int k0 = 0; k0 < 256; k0 += 32) {
        short8 b0 = *reinterpret_cast<const short8*>(&sh.G[col * TS + k0 + quad * 8]);
        short8 b1 = *reinterpret_cast<const short8*>(&sh.G[(16 + col) * TS + k0 + quad * 8]);
#pragma unroll
        for (int i = 0; i < 4; ++i) {
            short8 af = *reinterpret_cast<const short8*>(Wm + (size_t)(wave * 64 + i * 16 + col) * 256 + k0 + quad * 8);
            pacc[i][0] = __builtin_amdgcn_mfma_f32_16x16x32_bf16(af, b0, pacc[i][0], 0, 0, 0);
            pacc[i][1] = __builtin_amdgcn_mfma_f32_16x16x32_bf16(af, b1, pacc[i][1], 0, 0, 0);
        }
    }
    float* op = out + (size_t)b * C * N;
#pragma unroll
    for (int i = 0; i < 4; ++i) {
        int cr = wave * 64 + i * 16 + quad * 4;
        float bias[4];
#pragma unroll
        for (int r = 0; r < 4; ++r) bias[r] = bp[cr + r];
#pragma unroll
        for (int cf = 0; cf < 2; ++cf) {
            int n = n0 + cf * 16 + col;
#pragma unroll
            for (int r = 0; r < 4; ++r)
                op[(size_t)(cr + r) * N + n] = pacc[i][cf][r] + bias[r];
        }
    }
}

// ---------------------------------------------------------------------------
// Workspace (bytes):
//   [0, 32K)        sqg f32 [8][1024]
//   [32K, 160K)     Wpb bf16 [256][256]
//   [160K, +4M)     qo bf16 [8][1024][256]  (pixel-major, sq*SCALE folded)
//   +4M             ko bf16 [8][1024][256]  (pixel-major, sk folded)
//   +4M             vo bf16 [8][256][1024]  (d-major)
// ---------------------------------------------------------------------------
extern "C" void kernel_launch(void* const* d_in, const int* in_sizes, int n_in,
                              void* d_out, int out_size, void* d_ws, size_t ws_size,
                              hipStream_t stream)
{
    const float* x   = (const float*)d_in[0];
    const float* gq  = (const float*)d_in[1];
    const float* gk  = (const float*)d_in[2];
    const float* Wsq = (const float*)d_in[3];
    const float* bsq = (const float*)d_in[4];
    const float* Wsk = (const float*)d_in[5];
    const float* bsk = (const float*)d_in[6];
    const float* Wq  = (const float*)d_in[7];
    const float* bq  = (const float*)d_in[8];
    const float* Wk  = (const float*)d_in[9];
    const float* bk  = (const float*)d_in[10];
    const float* Wv  = (const float*)d_in[11];
    const float* bv  = (const float*)d_in[12];
    const float* Wp  = (const float*)d_in[13];
    const float* bp  = (const float*)d_in[14];

    char* ws = (char*)d_ws;
    float* sqg = (float*)ws;
    bf16* Wpb  = (bf16*)(ws + 32768);
    bf16* qo   = (bf16*)(ws + 163840);
    bf16* ko   = qo + (size_t)Bn * N * C;
    bf16* vo   = ko + (size_t)Bn * N * C;
    float* out = (float*)d_out;

    k_fused<<<260, 256, 0, stream>>>(x, gq, gk, Wsq, bsq, Wsk, bsk,
                                     Wq, bq, Wk, bk, Wv, bv, Wp,
                                     qo, ko, vo, Wpb, sqg);
    k_attnproj<<<256, 256, 0, stream>>>(qo, ko, vo, sqg, Wpb, bp, out);
}